// Round 4
// baseline (167.372 us; speedup 1.0000x reference)
//
#include <hip/hip_runtime.h>
#include <hip/hip_bf16.h>
#include <stdint.h>

#define T_TOK 8192
#define DIM   1024
#define NEXP  16
#define ESZ   256
#define TOPK  4
#define BM    128
#define BK    64
#define NPAIR (T_TOK*TOPK)                 // 32768
#define NBLK  128                          // hist/scatter blocks (256 pairs each)
#define MAXROWS (T_TOK*TOPK + NEXP*BM)     // 34816 padded assignment rows
#define MAXTILES (T_TOK*TOPK/BM + NEXP)    // 272

typedef __hip_bfloat16 bf16;
typedef short bf16x8 __attribute__((ext_vector_type(8)));
typedef float f32x4 __attribute__((ext_vector_type(4)));

__device__ __forceinline__ unsigned short f2bu(float f){
  __hip_bfloat16 b = __float2bfloat16(f);
  return *reinterpret_cast<unsigned short*>(&b);
}
__device__ __forceinline__ float bu2f(unsigned short u){
  __hip_bfloat16 b = *reinterpret_cast<__hip_bfloat16*>(&u);
  return __bfloat162float(b);
}

__device__ __forceinline__ void gload16(const void* g, void* l){
  __builtin_amdgcn_global_load_lds((const __attribute__((address_space(1))) void*)g,
                                   (__attribute__((address_space(3))) void*)l, 16, 0, 0);
}

// ---------------- gating: logits -> sigmoid -> top4, fused x->bf16 ----------
__global__ __launch_bounds__(256) void k_gate(const float* __restrict__ x,
    const float* __restrict__ wg, bf16* __restrict__ xb,
    int* __restrict__ sel_idx, float* __restrict__ sel_gate)
{
  const int wave = threadIdx.x >> 6, lane = threadIdx.x & 63;
  const int t = blockIdx.x*4 + wave;
  const float* xr = x + (size_t)t*DIM;
  float4 xv[4];
#pragma unroll
  for (int c=0;c<4;c++) xv[c] = *(const float4*)(xr + c*256 + lane*4);
#pragma unroll
  for (int c=0;c<4;c++){
    ushort4 o; o.x=f2bu(xv[c].x); o.y=f2bu(xv[c].y); o.z=f2bu(xv[c].z); o.w=f2bu(xv[c].w);
    *(ushort4*)((unsigned short*)xb + (size_t)t*DIM + c*256 + lane*4) = o;
  }
  float sg[NEXP];
#pragma unroll
  for (int e=0;e<NEXP;e++){
    const float* wr = wg + e*DIM;
    float p = 0.f;
#pragma unroll
    for (int c=0;c<4;c++){
      float4 w = *(const float4*)(wr + c*256 + lane*4);
      p += xv[c].x*w.x + xv[c].y*w.y + xv[c].z*w.z + xv[c].w*w.w;
    }
#pragma unroll
    for (int s=1;s<64;s<<=1) p += __shfl_xor(p, s);
    sg[e] = 1.f/(1.f + expf(-p));
  }
  if (lane==0){
    unsigned chosen = 0;
#pragma unroll
    for (int k=0;k<TOPK;k++){
      float best=-1.f; int bi=0;
#pragma unroll
      for (int e=0;e<NEXP;e++){
        float v = ((chosen>>e)&1u) ? -2.f : sg[e];
        if (v>best){best=v;bi=e;}
      }
      chosen |= 1u<<bi;
      sel_idx[t*TOPK+k]=bi; sel_gate[t*TOPK+k]=best;
    }
  }
}

// ------- merged fp32->bf16 transposes: keys (z<16) and values (z>=16) -------
__global__ __launch_bounds__(256) void k_transpose2(const float* __restrict__ keys,
    const float* __restrict__ values, bf16* __restrict__ kT, bf16* __restrict__ vT)
{
  __shared__ float tile[32][33];
  const int which = blockIdx.y >> 4, e = blockIdx.y & 15;
  const int R = which ? ESZ : DIM, C = which ? DIM : ESZ;
  const float* src = (which ? values : keys) + (size_t)e*DIM*ESZ;
  bf16* dst = (which ? vT : kT) + (size_t)e*DIM*ESZ;
  const int ctiles = C/32;
  const int r0 = (blockIdx.x / ctiles)*32, c0 = (blockIdx.x % ctiles)*32;
  const int tx = threadIdx.x & 31, ty = threadIdx.x >> 5;
#pragma unroll
  for (int i=0;i<4;i++){ int r = ty + i*8; tile[r][tx] = src[(size_t)(r0+r)*C + c0 + tx]; }
  __syncthreads();
#pragma unroll
  for (int i=0;i<4;i++){ int r = ty + i*8; dst[(size_t)(c0+r)*R + r0 + tx] = __float2bfloat16(tile[tx][r]); }
}

// ---------------- per-block histogram (LDS atomics only) --------------------
__global__ __launch_bounds__(256) void k_hist(const int* __restrict__ sel_idx,
    int* __restrict__ block_hist)
{
  __shared__ int h[NEXP];
  if (threadIdx.x < NEXP) h[threadIdx.x]=0;
  __syncthreads();
  atomicAdd(&h[sel_idx[blockIdx.x*256 + threadIdx.x]], 1);
  __syncthreads();
  if (threadIdx.x < NEXP) block_hist[blockIdx.x*NEXP + threadIdx.x] = h[threadIdx.x];
}

// ------- totals -> padded segments + tile map + per-block bases -------------
__global__ void k_meta(const int* __restrict__ block_hist,
    int* __restrict__ tile_expert, int* __restrict__ tile_rowstart,
    int* __restrict__ tile_segend, int* __restrict__ block_base)
{
  __shared__ int cnt[NEXP], seg[NEXP];
  const int tid = threadIdx.x;
  if (tid < NEXP){
    int s=0;
    for (int b=0;b<NBLK;b++) s += block_hist[b*NEXP + tid];
    cnt[tid]=s;
  }
  __syncthreads();
  if (tid==0){
    int off=0, tc=0;
    for (int e=0;e<NEXP;e++){
      seg[e]=off;
      int c = cnt[e];
      int nt = (c + BM - 1)/BM;
      for (int i=0;i<nt;i++){
        tile_expert[tc]=e; tile_rowstart[tc]=off+i*BM; tile_segend[tc]=off+c; tc++;
      }
      off += nt*BM;            // 128-padded segments: tiles never overlap experts
    }
    for (; tc<MAXTILES; tc++) tile_expert[tc]=-1;
  }
  __syncthreads();
  if (tid < NEXP){
    int s = seg[tid];
    for (int b=0;b<NBLK;b++){ block_base[b*NEXP + tid] = s; s += block_hist[b*NEXP + tid]; }
  }
}

// ------- deterministic scatter: ballot rank + wave prefix, no global atomics
__global__ __launch_bounds__(256) void k_scatter(const int* __restrict__ sel_idx,
    const float* __restrict__ sel_gate, const int* __restrict__ block_base,
    int* __restrict__ assign_token, float* __restrict__ assign_gate,
    int* __restrict__ inv_rows)
{
  __shared__ int wcnt[4][NEXP];
  const int p = blockIdx.x*256 + threadIdx.x;
  const int wave = threadIdx.x >> 6, lane = threadIdx.x & 63;
  const int e = sel_idx[p];
  const float g = sel_gate[p];
  int rank = 0;
#pragma unroll
  for (int ee=0; ee<NEXP; ee++){
    unsigned long long m = __ballot(e==ee);
    if (lane==0) wcnt[wave][ee] = (int)__popcll(m);
    if (e==ee) rank = (int)__popcll(m & ((1ull<<lane)-1ull));
  }
  __syncthreads();
  int pre = 0;
  for (int w=0; w<wave; w++) pre += wcnt[w][e];
  const int row = block_base[blockIdx.x*NEXP + e] + pre + rank;
  assign_token[row] = p >> 2;
  assign_gate[row]  = g;
  inv_rows[p] = row;
}

// ---------------- GEMM1: h = bf16( relu(Xg @ keys_e) * gate ) ---------------
// double-buffered prefetch K-loop; grid = (nb fastest, tile slow) for L2 reuse
__global__ __launch_bounds__(256) void k_gemm1(
    const bf16* __restrict__ xb, const bf16* __restrict__ kT,
    const int* __restrict__ assign_token, const float* __restrict__ assign_gate,
    const int* __restrict__ tile_expert, const int* __restrict__ tile_rowstart,
    const int* __restrict__ tile_segend, bf16* __restrict__ h)
{
  __shared__ char smem[65536];         // A0 A1 B0 B1, 16 KB each
  __shared__ int   tokens_s[BM];
  __shared__ float gates_s[BM];

  const int nb = blockIdx.x, tile = blockIdx.y;
  const int e = tile_expert[tile];
  if (e < 0) return;
  const int row0 = tile_rowstart[tile];
  const int segend = tile_segend[tile];
  const int tid = threadIdx.x, wave = tid>>6, lane = tid&63;

  if (tid < BM){
    int rg = row0 + tid;
    bool vld = rg < segend;
    tokens_s[tid] = vld ? assign_token[rg] : 0;
    gates_s[tid]  = vld ? assign_gate[rg] : 0.f;
  }
  __syncthreads();

  char* As = smem;             // + cur*16384
  char* Bs = smem + 32768;     // + cur*16384
  const bf16* gA[4]; const bf16* gB[4]; int lo[4];
#pragma unroll
  for (int i=0;i<4;i++){
    int rl = (wave*4+i)*8 + (lane>>3);
    int c  = (lane&7) ^ (rl&7);                 // source-side XOR pre-swizzle
    gA[i] = xb + (size_t)tokens_s[rl]*DIM + c*8;
    gB[i] = kT + ((size_t)e*ESZ + nb*BM + rl)*DIM + c*8;
    lo[i] = (wave*4+i)*1024;
  }

  f32x4 acc[4][4];
#pragma unroll
  for (int m=0;m<4;m++)
#pragma unroll
    for (int n=0;n<4;n++) acc[m][n] = {0.f,0.f,0.f,0.f};

  const int wr0 = (wave>>1)*64, wc0 = (wave&1)*64;
  const int NT = DIM/BK;       // 16

#pragma unroll
  for (int i=0;i<4;i++){ gload16(gA[i], As + lo[i]); gload16(gB[i], Bs + lo[i]); }

  for (int kt=0; kt<NT; ++kt){
    const int cur = kt & 1;
    if (kt+1 < NT){
      const int nxt = cur^1;
#pragma unroll
      for (int i=0;i<4;i++){
        gload16(gA[i] + (kt+1)*BK, As + nxt*16384 + lo[i]);
        gload16(gB[i] + (kt+1)*BK, Bs + nxt*16384 + lo[i]);
      }
      asm volatile("s_waitcnt vmcnt(8)" ::: "memory");   // drain PREVIOUS tile only
    } else {
      asm volatile("s_waitcnt vmcnt(0)" ::: "memory");
    }
    __syncthreads();
    const char* Ab = As + cur*16384; const char* Bb = Bs + cur*16384;
#pragma unroll
    for (int kk=0;kk<2;kk++){
      bf16x8 af[4], bfr[4];
#pragma unroll
      for (int m=0;m<4;m++){
        int row = wr0 + m*16 + (lane&15);
        int kb  = kk*64 + (lane>>4)*16;
        af[m] = *(const bf16x8*)(Ab + row*128 + (kb ^ ((row&7)<<4)));
      }
#pragma unroll
      for (int n=0;n<4;n++){
        int col = wc0 + n*16 + (lane&15);
        int kb  = kk*64 + (lane>>4)*16;
        bfr[n] = *(const bf16x8*)(Bb + col*128 + (kb ^ ((col&7)<<4)));
      }
#pragma unroll
      for (int m=0;m<4;m++)
#pragma unroll
        for (int n=0;n<4;n++)
          acc[m][n] = __builtin_amdgcn_mfma_f32_16x16x32_bf16(af[m], bfr[n], acc[m][n], 0,0,0);
    }
    __syncthreads();
  }

#pragma unroll
  for (int m=0;m<4;m++)
#pragma unroll
    for (int n=0;n<4;n++){
      int col = wc0 + n*16 + (lane&15);
#pragma unroll
      for (int j=0;j<4;j++){
        int rloc = wr0 + m*16 + ((lane>>4)<<2) + j;
        float v = fmaxf(acc[m][n][j], 0.f) * gates_s[rloc];
        h[(size_t)(row0 + rloc)*ESZ + nb*BM + col] = __float2bfloat16(v);
      }
    }
}

// -------- GEMM2: partial[row] = bf16( h[row] @ values_e )  (no atomics) -----
__global__ __launch_bounds__(256) void k_gemm2(
    const bf16* __restrict__ h, const bf16* __restrict__ vT,
    const int* __restrict__ tile_expert, const int* __restrict__ tile_rowstart,
    bf16* __restrict__ partial)
{
  __shared__ char smem[65536];

  const int nb = blockIdx.x, tile = blockIdx.y;
  const int e = tile_expert[tile];
  if (e < 0) return;
  const int row0 = tile_rowstart[tile];
  const int tid = threadIdx.x, wave = tid>>6, lane = tid&63;

  char* As = smem;
  char* Bs = smem + 32768;
  const bf16* gA[4]; const bf16* gB[4]; int lo[4];
#pragma unroll
  for (int i=0;i<4;i++){
    int rl = (wave*4+i)*8 + (lane>>3);
    int c  = (lane&7) ^ (rl&7);
    gA[i] = h + (size_t)(row0 + rl)*ESZ + c*8;
    gB[i] = vT + ((size_t)e*DIM + nb*BM + rl)*ESZ + c*8;
    lo[i] = (wave*4+i)*1024;
  }

  f32x4 acc[4][4];
#pragma unroll
  for (int m=0;m<4;m++)
#pragma unroll
    for (int n=0;n<4;n++) acc[m][n] = {0.f,0.f,0.f,0.f};

  const int wr0 = (wave>>1)*64, wc0 = (wave&1)*64;
  const int NT = ESZ/BK;       // 4

#pragma unroll
  for (int i=0;i<4;i++){ gload16(gA[i], As + lo[i]); gload16(gB[i], Bs + lo[i]); }

  for (int kt=0; kt<NT; ++kt){
    const int cur = kt & 1;
    if (kt+1 < NT){
      const int nxt = cur^1;
#pragma unroll
      for (int i=0;i<4;i++){
        gload16(gA[i] + (kt+1)*BK, As + nxt*16384 + lo[i]);
        gload16(gB[i] + (kt+1)*BK, Bs + nxt*16384 + lo[i]);
      }
      asm volatile("s_waitcnt vmcnt(8)" ::: "memory");
    } else {
      asm volatile("s_waitcnt vmcnt(0)" ::: "memory");
    }
    __syncthreads();
    const char* Ab = As + cur*16384; const char* Bb = Bs + cur*16384;
#pragma unroll
    for (int kk=0;kk<2;kk++){
      bf16x8 af[4], bfr[4];
#pragma unroll
      for (int m=0;m<4;m++){
        int row = wr0 + m*16 + (lane&15);
        int kb  = kk*64 + (lane>>4)*16;
        af[m] = *(const bf16x8*)(Ab + row*128 + (kb ^ ((row&7)<<4)));
      }
#pragma unroll
      for (int n=0;n<4;n++){
        int col = wc0 + n*16 + (lane&15);
        int kb  = kk*64 + (lane>>4)*16;
        bfr[n] = *(const bf16x8*)(Bb + col*128 + (kb ^ ((col&7)<<4)));
      }
#pragma unroll
      for (int m=0;m<4;m++)
#pragma unroll
        for (int n=0;n<4;n++)
          acc[m][n] = __builtin_amdgcn_mfma_f32_16x16x32_bf16(af[m], bfr[n], acc[m][n], 0,0,0);
    }
    __syncthreads();
  }

#pragma unroll
  for (int m=0;m<4;m++)
#pragma unroll
    for (int n=0;n<4;n++){
      int col = wc0 + n*16 + (lane&15);
#pragma unroll
      for (int j=0;j<4;j++){
        int rloc = wr0 + m*16 + ((lane>>4)<<2) + j;
        partial[(size_t)(row0 + rloc)*DIM + nb*BM + col] = __float2bfloat16(acc[m][n][j]);
      }
    }
}

// -------- reduce: out[t] = sum_k partial[inv_rows[t,k]] ---------------------
__global__ __launch_bounds__(256) void k_reduce(const bf16* __restrict__ partial,
    const int* __restrict__ inv_rows, float* __restrict__ out)
{
  const int t = blockIdx.x;
  const int c0 = threadIdx.x * 4;
  int rows[TOPK];
#pragma unroll
  for (int k=0;k<TOPK;k++) rows[k] = inv_rows[t*TOPK+k];
  float a0=0.f,a1=0.f,a2=0.f,a3=0.f;
#pragma unroll
  for (int k=0;k<TOPK;k++){
    ushort4 v = *(const ushort4*)((const unsigned short*)partial + (size_t)rows[k]*DIM + c0);
    a0 += bu2f(v.x); a1 += bu2f(v.y); a2 += bu2f(v.z); a3 += bu2f(v.w);
  }
  float4 o = {a0,a1,a2,a3};
  *(float4*)(out + (size_t)t*DIM + c0) = o;
}

// ---------------------------------------------------------------------------
extern "C" void kernel_launch(void* const* d_in, const int* in_sizes, int n_in,
                              void* d_out, int out_size, void* d_ws, size_t ws_size,
                              hipStream_t stream)
{
  const float* x      = (const float*)d_in[0];
  const float* wg     = (const float*)d_in[1];
  const float* keys   = (const float*)d_in[2];
  const float* values = (const float*)d_in[3];
  float* out = (float*)d_out;

  char* ws = (char*)d_ws;
  size_t off = 0;
  bf16* vT   = (bf16*)(ws+off); off += (size_t)NEXP*DIM*ESZ*2;   // 8 MB
  bf16* hbuf = (bf16*)(ws+off); off += (size_t)MAXROWS*ESZ*2;    // 17.8 MB
  int*   sel_idx      = (int*)  (ws+off); off += (size_t)NPAIR*4;
  float* sel_gate     = (float*)(ws+off); off += (size_t)NPAIR*4;
  int*   assign_token = (int*)  (ws+off); off += (size_t)MAXROWS*4;
  float* assign_gate  = (float*)(ws+off); off += (size_t)MAXROWS*4;
  int*   inv_rows     = (int*)  (ws+off); off += (size_t)NPAIR*4;
  int*   block_hist   = (int*)  (ws+off); off += (size_t)NBLK*NEXP*4;
  int*   block_base   = (int*)  (ws+off); off += (size_t)NBLK*NEXP*4;
  int*   tile_expert  = (int*)  (ws+off); off += 4096;
  int*   tile_rowstart= (int*)  (ws+off); off += 4096;
  int*   tile_segend  = (int*)  (ws+off); off += 4096;
  // partial is live only AFTER gemm1; xb/kT are dead after gemm1 -> alias them
  // into partial's tail to cap total workspace at ~98 MB.
  const size_t PARTIAL_BYTES = (size_t)MAXROWS*DIM*2;            // 71.3 MB
  const size_t XB_BYTES = (size_t)T_TOK*DIM*2;                   // 16.8 MB
  const size_t KT_BYTES = (size_t)NEXP*ESZ*DIM*2;                // 8.4 MB
  bf16* partial = (bf16*)(ws+off); off += PARTIAL_BYTES;
  bf16* xb = (bf16*)((char*)partial + PARTIAL_BYTES - XB_BYTES - KT_BYTES);
  bf16* kT = (bf16*)((char*)partial + PARTIAL_BYTES - KT_BYTES);

  k_gate<<<T_TOK/4, 256, 0, stream>>>(x, wg, xb, sel_idx, sel_gate);
  k_transpose2<<<dim3(256, NEXP*2), 256, 0, stream>>>(keys, values, kT, vT);
  k_hist<<<NBLK, 256, 0, stream>>>(sel_idx, block_hist);
  k_meta<<<1, 256, 0, stream>>>(block_hist, tile_expert, tile_rowstart, tile_segend, block_base);
  k_scatter<<<NBLK, 256, 0, stream>>>(sel_idx, sel_gate, block_base, assign_token,
      assign_gate, inv_rows);
  k_gemm1<<<dim3(ESZ/BM, MAXTILES), 256, 0, stream>>>(xb, kT, assign_token, assign_gate,
      tile_expert, tile_rowstart, tile_segend, hbuf);
  k_gemm2<<<dim3(DIM/BM, MAXTILES), 256, 0, stream>>>(hbuf, vT,
      tile_expert, tile_rowstart, partial);
  k_reduce<<<T_TOK, 256, 0, stream>>>(partial, inv_rows, out);
}

// Round 5
// 164.611 us; speedup vs baseline: 1.0168x; 1.0168x over previous
//
#include <hip/hip_runtime.h>
#include <hip/hip_bf16.h>
#include <stdint.h>

#define T_TOK 8192
#define DIM   1024
#define NEXP  16
#define ESZ   256
#define TOPK  4
#define BM    128
#define BK    64
#define NPAIR (T_TOK*TOPK)                 // 32768
#define NBLK  128                          // hist/scatter blocks (256 pairs each)
#define MAXROWS (T_TOK*TOPK + NEXP*BM)     // 34816 padded assignment rows
#define MAXTILES (T_TOK*TOPK/BM + NEXP)    // 272

typedef __hip_bfloat16 bf16;
typedef short bf16x8 __attribute__((ext_vector_type(8)));
typedef float f32x4 __attribute__((ext_vector_type(4)));

__device__ __forceinline__ unsigned short f2bu(float f){
  __hip_bfloat16 b = __float2bfloat16(f);
  return *reinterpret_cast<unsigned short*>(&b);
}
__device__ __forceinline__ float bu2f(unsigned short u){
  __hip_bfloat16 b = *reinterpret_cast<__hip_bfloat16*>(&u);
  return __bfloat162float(b);
}

__device__ __forceinline__ void gload16(const void* g, void* l){
  __builtin_amdgcn_global_load_lds((const __attribute__((address_space(1))) void*)g,
                                   (__attribute__((address_space(3))) void*)l, 16, 0, 0);
}

// ---------------- gating: logits -> sigmoid -> top4, fused x->bf16 ----------
__global__ __launch_bounds__(256) void k_gate(const float* __restrict__ x,
    const float* __restrict__ wg, bf16* __restrict__ xb,
    int* __restrict__ sel_idx, float* __restrict__ sel_gate)
{
  const int wave = threadIdx.x >> 6, lane = threadIdx.x & 63;
  const int t = blockIdx.x*4 + wave;
  const float* xr = x + (size_t)t*DIM;
  float4 xv[4];
#pragma unroll
  for (int c=0;c<4;c++) xv[c] = *(const float4*)(xr + c*256 + lane*4);
#pragma unroll
  for (int c=0;c<4;c++){
    ushort4 o; o.x=f2bu(xv[c].x); o.y=f2bu(xv[c].y); o.z=f2bu(xv[c].z); o.w=f2bu(xv[c].w);
    *(ushort4*)((unsigned short*)xb + (size_t)t*DIM + c*256 + lane*4) = o;
  }
  float sg[NEXP];
#pragma unroll
  for (int e=0;e<NEXP;e++){
    const float* wr = wg + e*DIM;
    float p = 0.f;
#pragma unroll
    for (int c=0;c<4;c++){
      float4 w = *(const float4*)(wr + c*256 + lane*4);
      p += xv[c].x*w.x + xv[c].y*w.y + xv[c].z*w.z + xv[c].w*w.w;
    }
#pragma unroll
    for (int s=1;s<64;s<<=1) p += __shfl_xor(p, s);
    sg[e] = 1.f/(1.f + expf(-p));
  }
  if (lane==0){
    unsigned chosen = 0;
#pragma unroll
    for (int k=0;k<TOPK;k++){
      float best=-1.f; int bi=0;
#pragma unroll
      for (int e=0;e<NEXP;e++){
        float v = ((chosen>>e)&1u) ? -2.f : sg[e];
        if (v>best){best=v;bi=e;}
      }
      chosen |= 1u<<bi;
      sel_idx[t*TOPK+k]=bi; sel_gate[t*TOPK+k]=best;
    }
  }
}

// ------- merged fp32->bf16 transposes: keys (z<16) and values (z>=16) -------
__global__ __launch_bounds__(256) void k_transpose2(const float* __restrict__ keys,
    const float* __restrict__ values, bf16* __restrict__ kT, bf16* __restrict__ vT)
{
  __shared__ float tile[32][33];
  const int which = blockIdx.y >> 4, e = blockIdx.y & 15;
  const int R = which ? ESZ : DIM, C = which ? DIM : ESZ;
  const float* src = (which ? values : keys) + (size_t)e*DIM*ESZ;
  bf16* dst = (which ? vT : kT) + (size_t)e*DIM*ESZ;
  const int ctiles = C/32;
  const int r0 = (blockIdx.x / ctiles)*32, c0 = (blockIdx.x % ctiles)*32;
  const int tx = threadIdx.x & 31, ty = threadIdx.x >> 5;
#pragma unroll
  for (int i=0;i<4;i++){ int r = ty + i*8; tile[r][tx] = src[(size_t)(r0+r)*C + c0 + tx]; }
  __syncthreads();
#pragma unroll
  for (int i=0;i<4;i++){ int r = ty + i*8; dst[(size_t)(c0+r)*R + r0 + tx] = __float2bfloat16(tile[tx][r]); }
}

// ---------------- per-block histogram (LDS atomics only) --------------------
__global__ __launch_bounds__(256) void k_hist(const int* __restrict__ sel_idx,
    int* __restrict__ block_hist)
{
  __shared__ int h[NEXP];
  if (threadIdx.x < NEXP) h[threadIdx.x]=0;
  __syncthreads();
  atomicAdd(&h[sel_idx[blockIdx.x*256 + threadIdx.x]], 1);
  __syncthreads();
  if (threadIdx.x < NEXP) block_hist[blockIdx.x*NEXP + threadIdx.x] = h[threadIdx.x];
}

// ------- totals -> padded segments + tile map + per-block bases -------------
__global__ void k_meta(const int* __restrict__ block_hist,
    int* __restrict__ tile_expert, int* __restrict__ tile_rowstart,
    int* __restrict__ tile_segend, int* __restrict__ block_base)
{
  __shared__ int cnt[NEXP], seg[NEXP];
  const int tid = threadIdx.x;
  if (tid < NEXP){
    int s=0;
    for (int b=0;b<NBLK;b++) s += block_hist[b*NEXP + tid];
    cnt[tid]=s;
  }
  __syncthreads();
  if (tid==0){
    int off=0, tc=0;
    for (int e=0;e<NEXP;e++){
      seg[e]=off;
      int c = cnt[e];
      int nt = (c + BM - 1)/BM;
      for (int i=0;i<nt;i++){
        tile_expert[tc]=e; tile_rowstart[tc]=off+i*BM; tile_segend[tc]=off+c; tc++;
      }
      off += nt*BM;            // 128-padded segments: tiles never overlap experts
    }
    for (; tc<MAXTILES; tc++) tile_expert[tc]=-1;
  }
  __syncthreads();
  if (tid < NEXP){
    int s = seg[tid];
    for (int b=0;b<NBLK;b++){ block_base[b*NEXP + tid] = s; s += block_hist[b*NEXP + tid]; }
  }
}

// ------- deterministic scatter: ballot rank + wave prefix, no global atomics
__global__ __launch_bounds__(256) void k_scatter(const int* __restrict__ sel_idx,
    const float* __restrict__ sel_gate, const int* __restrict__ block_base,
    int* __restrict__ assign_token, float* __restrict__ assign_gate,
    int* __restrict__ inv_rows)
{
  __shared__ int wcnt[4][NEXP];
  const int p = blockIdx.x*256 + threadIdx.x;
  const int wave = threadIdx.x >> 6, lane = threadIdx.x & 63;
  const int e = sel_idx[p];
  const float g = sel_gate[p];
  int rank = 0;
#pragma unroll
  for (int ee=0; ee<NEXP; ee++){
    unsigned long long m = __ballot(e==ee);
    if (lane==0) wcnt[wave][ee] = (int)__popcll(m);
    if (e==ee) rank = (int)__popcll(m & ((1ull<<lane)-1ull));
  }
  __syncthreads();
  int pre = 0;
  for (int w=0; w<wave; w++) pre += wcnt[w][e];
  const int row = block_base[blockIdx.x*NEXP + e] + pre + rank;
  assign_token[row] = p >> 2;
  assign_gate[row]  = g;
  inv_rows[p] = row;
}

// ---------------- GEMM1: h = bf16( relu(Xg @ keys_e) * gate ) ---------------
// T3/T4-minimum pipeline: raw s_barrier (no implicit vmcnt drain), one
// barrier + one post-compute vmcnt(0) per K-step.
__global__ __launch_bounds__(256) void k_gemm1(
    const bf16* __restrict__ xb, const bf16* __restrict__ kT,
    const int* __restrict__ assign_token, const float* __restrict__ assign_gate,
    const int* __restrict__ tile_expert, const int* __restrict__ tile_rowstart,
    const int* __restrict__ tile_segend, bf16* __restrict__ h)
{
  __shared__ char smem[65536];         // A0 A1 B0 B1, 16 KB each
  __shared__ int   tokens_s[BM];
  __shared__ float gates_s[BM];

  const int nb = blockIdx.x, tile = blockIdx.y;
  const int e = tile_expert[tile];
  if (e < 0) return;
  const int row0 = tile_rowstart[tile];
  const int segend = tile_segend[tile];
  const int tid = threadIdx.x, wave = tid>>6, lane = tid&63;

  if (tid < BM){
    int rg = row0 + tid;
    bool vld = rg < segend;
    tokens_s[tid] = vld ? assign_token[rg] : 0;
    gates_s[tid]  = vld ? assign_gate[rg] : 0.f;
  }
  __syncthreads();

  char* As = smem;             // + cur*16384
  char* Bs = smem + 32768;     // + cur*16384
  const bf16* gA[4]; const bf16* gB[4]; int lo[4];
#pragma unroll
  for (int i=0;i<4;i++){
    int rl = (wave*4+i)*8 + (lane>>3);
    int c  = (lane&7) ^ (rl&7);                 // source-side XOR pre-swizzle
    gA[i] = xb + (size_t)tokens_s[rl]*DIM + c*8;
    gB[i] = kT + ((size_t)e*ESZ + nb*BM + rl)*DIM + c*8;
    lo[i] = (wave*4+i)*1024;
  }

  f32x4 acc[4][4];
#pragma unroll
  for (int m=0;m<4;m++)
#pragma unroll
    for (int n=0;n<4;n++) acc[m][n] = {0.f,0.f,0.f,0.f};

  const int wr0 = (wave>>1)*64, wc0 = (wave&1)*64;
  const int NT = DIM/BK;       // 16

#pragma unroll
  for (int i=0;i<4;i++){ gload16(gA[i], As + lo[i]); gload16(gB[i], Bs + lo[i]); }
  asm volatile("s_waitcnt vmcnt(0)" ::: "memory");
  __builtin_amdgcn_s_barrier();

  for (int kt=0; kt<NT; ++kt){
    const int cur = kt & 1;
    if (kt+1 < NT){
      const int nxt = cur^1;
#pragma unroll
      for (int i=0;i<4;i++){
        gload16(gA[i] + (kt+1)*BK, As + nxt*16384 + lo[i]);
        gload16(gB[i] + (kt+1)*BK, Bs + nxt*16384 + lo[i]);
      }
    }
    const char* Ab = As + cur*16384; const char* Bb = Bs + cur*16384;
#pragma unroll
    for (int kk=0;kk<2;kk++){
      bf16x8 af[4], bfr[4];
#pragma unroll
      for (int m=0;m<4;m++){
        int row = wr0 + m*16 + (lane&15);
        int kb  = kk*64 + (lane>>4)*16;
        af[m] = *(const bf16x8*)(Ab + row*128 + (kb ^ ((row&7)<<4)));
      }
#pragma unroll
      for (int n=0;n<4;n++){
        int col = wc0 + n*16 + (lane&15);
        int kb  = kk*64 + (lane>>4)*16;
        bfr[n] = *(const bf16x8*)(Bb + col*128 + (kb ^ ((col&7)<<4)));
      }
#pragma unroll
      for (int m=0;m<4;m++)
#pragma unroll
        for (int n=0;n<4;n++)
          acc[m][n] = __builtin_amdgcn_mfma_f32_16x16x32_bf16(af[m], bfr[n], acc[m][n], 0,0,0);
    }
    // drain this step's prefetch AFTER compute (latency hidden under MFMA),
    // then raw barrier (no compiler-inserted full drain).
    asm volatile("s_waitcnt vmcnt(0)" ::: "memory");
    __builtin_amdgcn_s_barrier();
  }

#pragma unroll
  for (int m=0;m<4;m++)
#pragma unroll
    for (int n=0;n<4;n++){
      int col = wc0 + n*16 + (lane&15);
#pragma unroll
      for (int j=0;j<4;j++){
        int rloc = wr0 + m*16 + ((lane>>4)<<2) + j;
        float v = fmaxf(acc[m][n][j], 0.f) * gates_s[rloc];
        h[(size_t)(row0 + rloc)*ESZ + nb*BM + col] = __float2bfloat16(v);
      }
    }
}

// -------- GEMM2: partial[row] = bf16( h[row] @ values_e )  (no atomics) -----
__global__ __launch_bounds__(256) void k_gemm2(
    const bf16* __restrict__ h, const bf16* __restrict__ vT,
    const int* __restrict__ tile_expert, const int* __restrict__ tile_rowstart,
    bf16* __restrict__ partial)
{
  __shared__ char smem[65536];

  const int nb = blockIdx.x, tile = blockIdx.y;
  const int e = tile_expert[tile];
  if (e < 0) return;
  const int row0 = tile_rowstart[tile];
  const int tid = threadIdx.x, wave = tid>>6, lane = tid&63;

  char* As = smem;
  char* Bs = smem + 32768;
  const bf16* gA[4]; const bf16* gB[4]; int lo[4];
#pragma unroll
  for (int i=0;i<4;i++){
    int rl = (wave*4+i)*8 + (lane>>3);
    int c  = (lane&7) ^ (rl&7);
    gA[i] = h + (size_t)(row0 + rl)*ESZ + c*8;
    gB[i] = vT + ((size_t)e*DIM + nb*BM + rl)*ESZ + c*8;
    lo[i] = (wave*4+i)*1024;
  }

  f32x4 acc[4][4];
#pragma unroll
  for (int m=0;m<4;m++)
#pragma unroll
    for (int n=0;n<4;n++) acc[m][n] = {0.f,0.f,0.f,0.f};

  const int wr0 = (wave>>1)*64, wc0 = (wave&1)*64;
  const int NT = ESZ/BK;       // 4

#pragma unroll
  for (int i=0;i<4;i++){ gload16(gA[i], As + lo[i]); gload16(gB[i], Bs + lo[i]); }
  asm volatile("s_waitcnt vmcnt(0)" ::: "memory");
  __builtin_amdgcn_s_barrier();

  for (int kt=0; kt<NT; ++kt){
    const int cur = kt & 1;
    if (kt+1 < NT){
      const int nxt = cur^1;
#pragma unroll
      for (int i=0;i<4;i++){
        gload16(gA[i] + (kt+1)*BK, As + nxt*16384 + lo[i]);
        gload16(gB[i] + (kt+1)*BK, Bs + nxt*16384 + lo[i]);
      }
    }
    const char* Ab = As + cur*16384; const char* Bb = Bs + cur*16384;
#pragma unroll
    for (int kk=0;kk<2;kk++){
      bf16x8 af[4], bfr[4];
#pragma unroll
      for (int m=0;m<4;m++){
        int row = wr0 + m*16 + (lane&15);
        int kb  = kk*64 + (lane>>4)*16;
        af[m] = *(const bf16x8*)(Ab + row*128 + (kb ^ ((row&7)<<4)));
      }
#pragma unroll
      for (int n=0;n<4;n++){
        int col = wc0 + n*16 + (lane&15);
        int kb  = kk*64 + (lane>>4)*16;
        bfr[n] = *(const bf16x8*)(Bb + col*128 + (kb ^ ((col&7)<<4)));
      }
#pragma unroll
      for (int m=0;m<4;m++)
#pragma unroll
        for (int n=0;n<4;n++)
          acc[m][n] = __builtin_amdgcn_mfma_f32_16x16x32_bf16(af[m], bfr[n], acc[m][n], 0,0,0);
    }
    asm volatile("s_waitcnt vmcnt(0)" ::: "memory");
    __builtin_amdgcn_s_barrier();
  }

#pragma unroll
  for (int m=0;m<4;m++)
#pragma unroll
    for (int n=0;n<4;n++){
      int col = wc0 + n*16 + (lane&15);
#pragma unroll
      for (int j=0;j<4;j++){
        int rloc = wr0 + m*16 + ((lane>>4)<<2) + j;
        partial[(size_t)(row0 + rloc)*DIM + nb*BM + col] = __float2bfloat16(acc[m][n][j]);
      }
    }
}

// -------- reduce: out[t] = sum_k partial[inv_rows[t,k]] ---------------------
__global__ __launch_bounds__(256) void k_reduce(const bf16* __restrict__ partial,
    const int* __restrict__ inv_rows, float* __restrict__ out)
{
  const int t = blockIdx.x;
  const int c0 = threadIdx.x * 4;
  int rows[TOPK];
#pragma unroll
  for (int k=0;k<TOPK;k++) rows[k] = inv_rows[t*TOPK+k];
  float a0=0.f,a1=0.f,a2=0.f,a3=0.f;
#pragma unroll
  for (int k=0;k<TOPK;k++){
    ushort4 v = *(const ushort4*)((const unsigned short*)partial + (size_t)rows[k]*DIM + c0);
    a0 += bu2f(v.x); a1 += bu2f(v.y); a2 += bu2f(v.z); a3 += bu2f(v.w);
  }
  float4 o = {a0,a1,a2,a3};
  *(float4*)(out + (size_t)t*DIM + c0) = o;
}

// ---------------------------------------------------------------------------
extern "C" void kernel_launch(void* const* d_in, const int* in_sizes, int n_in,
                              void* d_out, int out_size, void* d_ws, size_t ws_size,
                              hipStream_t stream)
{
  const float* x      = (const float*)d_in[0];
  const float* wg     = (const float*)d_in[1];
  const float* keys   = (const float*)d_in[2];
  const float* values = (const float*)d_in[3];
  float* out = (float*)d_out;

  char* ws = (char*)d_ws;
  size_t off = 0;
  bf16* vT   = (bf16*)(ws+off); off += (size_t)NEXP*DIM*ESZ*2;   // 8 MB
  bf16* hbuf = (bf16*)(ws+off); off += (size_t)MAXROWS*ESZ*2;    // 17.8 MB
  int*   sel_idx      = (int*)  (ws+off); off += (size_t)NPAIR*4;
  float* sel_gate     = (float*)(ws+off); off += (size_t)NPAIR*4;
  int*   assign_token = (int*)  (ws+off); off += (size_t)MAXROWS*4;
  float* assign_gate  = (float*)(ws+off); off += (size_t)MAXROWS*4;
  int*   inv_rows     = (int*)  (ws+off); off += (size_t)NPAIR*4;
  int*   block_hist   = (int*)  (ws+off); off += (size_t)NBLK*NEXP*4;
  int*   block_base   = (int*)  (ws+off); off += (size_t)NBLK*NEXP*4;
  int*   tile_expert  = (int*)  (ws+off); off += 4096;
  int*   tile_rowstart= (int*)  (ws+off); off += 4096;
  int*   tile_segend  = (int*)  (ws+off); off += 4096;
  // partial is live only AFTER gemm1; xb/kT are dead after gemm1 -> alias them
  // into partial's tail to cap total workspace at ~98 MB.
  const size_t PARTIAL_BYTES = (size_t)MAXROWS*DIM*2;            // 71.3 MB
  const size_t XB_BYTES = (size_t)T_TOK*DIM*2;                   // 16.8 MB
  const size_t KT_BYTES = (size_t)NEXP*ESZ*DIM*2;                // 8.4 MB
  bf16* partial = (bf16*)(ws+off); off += PARTIAL_BYTES;
  bf16* xb = (bf16*)((char*)partial + PARTIAL_BYTES - XB_BYTES - KT_BYTES);
  bf16* kT = (bf16*)((char*)partial + PARTIAL_BYTES - KT_BYTES);

  k_gate<<<T_TOK/4, 256, 0, stream>>>(x, wg, xb, sel_idx, sel_gate);
  k_transpose2<<<dim3(256, NEXP*2), 256, 0, stream>>>(keys, values, kT, vT);
  k_hist<<<NBLK, 256, 0, stream>>>(sel_idx, block_hist);
  k_meta<<<1, 256, 0, stream>>>(block_hist, tile_expert, tile_rowstart, tile_segend, block_base);
  k_scatter<<<NBLK, 256, 0, stream>>>(sel_idx, sel_gate, block_base, assign_token,
      assign_gate, inv_rows);
  k_gemm1<<<dim3(ESZ/BM, MAXTILES), 256, 0, stream>>>(xb, kT, assign_token, assign_gate,
      tile_expert, tile_rowstart, tile_segend, hbuf);
  k_gemm2<<<dim3(DIM/BM, MAXTILES), 256, 0, stream>>>(hbuf, vT,
      tile_expert, tile_rowstart, partial);
  k_reduce<<<T_TOK, 256, 0, stream>>>(partial, inv_rows, out);
}